// Round 3
// baseline (504.375 us; speedup 1.0000x reference)
//
#include <hip/hip_runtime.h>
#include <hip/hip_bf16.h>

#define P 7
#define CCH 256
#define NPIX 49
#define KTOT 2304
#define THREADS 512

typedef __bf16 bf16x8 __attribute__((ext_vector_type(8)));
typedef float f32x4 __attribute__((ext_vector_type(4)));

__device__ __forceinline__ unsigned short f2bf(float f) {
    unsigned int u = __float_as_uint(f);
    unsigned int r = (u + 0x7fffu + ((u >> 16) & 1u)) >> 16;
    return (unsigned short)r;
}
__device__ __forceinline__ float blo(unsigned int u) { return __uint_as_float(u << 16); }
__device__ __forceinline__ float bhi(unsigned int u) { return __uint_as_float(u & 0xffff0000u); }

// NCHW f32 -> NHWC bf16 (per level), 32x32 tile transpose over (c,x)
__global__ void nhwc_transpose_kernel(const float* __restrict__ src,
                                      unsigned short* __restrict__ dst,
                                      int H, int W) {
    __shared__ float tile[32][33];
    int x0 = blockIdx.x * 32;
    int c0 = blockIdx.y * 32;
    int bz = blockIdx.z;            // b*H + y
    int b = bz / H, y = bz - b * H;
    int tx = threadIdx.x & 31, ty = threadIdx.x >> 5;   // 256 threads
    const float* s = src + ((size_t)(b * CCH + c0) * H + y) * W + x0;
#pragma unroll
    for (int j = 0; j < 4; ++j) {
        int row = ty + j * 8;                       // c offset
        tile[row][tx] = s[(size_t)row * H * W + tx];
    }
    __syncthreads();
    unsigned short* d = dst + ((size_t)bz * W + x0) * CCH + c0;
#pragma unroll
    for (int j = 0; j < 4; ++j) {
        int row = ty + j * 8;                       // x offset
        d[(size_t)row * CCH + tx] = f2bf(tile[tx][row]);
    }
}

// w[co][ci][ky][kx] f32 -> Bt[co][k] bf16 with k = (ky*3+kx)*256 + ci
__global__ void wtrans_kernel(const float* __restrict__ pre_w,
                              const float* __restrict__ post_w,
                              unsigned short* __restrict__ btpre,
                              unsigned short* __restrict__ btpost) {
    int idx = blockIdx.x * 256 + threadIdx.x;
    const int total = CCH * KTOT;
    if (idx >= 2 * total) return;
    const float* w = pre_w;
    unsigned short* o = btpre;
    int r = idx;
    if (r >= total) { r -= total; w = post_w; o = btpost; }
    int co = r / KTOT, k = r - co * KTOT;
    int t = k >> 8, ci = k & 255;
    o[r] = f2bf(w[(size_t)(co * CCH + ci) * 9 + t]);
}

__launch_bounds__(THREADS, 2)
__global__ void fused_roi_kernel(const float* __restrict__ rois,
                                 const unsigned short* __restrict__ nh0,
                                 const unsigned short* __restrict__ nh1,
                                 const unsigned short* __restrict__ nh2,
                                 const unsigned short* __restrict__ nh3,
                                 const float* __restrict__ raw0,
                                 const float* __restrict__ raw1,
                                 const float* __restrict__ raw2,
                                 const float* __restrict__ raw3,
                                 int modes,
                                 const unsigned short* __restrict__ btpre,
                                 const unsigned short* __restrict__ btpost,
                                 const float* __restrict__ pre_b,
                                 const float* __restrict__ post_b,
                                 float* __restrict__ out) {
    // rows 0..48: 7x7x256 bf16 tile (512B rows, XOR-swizzled); row 49: zeros
    __shared__ __align__(16) char lds[50 * 512];

    int roi  = blockIdx.x;
    int tid  = threadIdx.x;
    int lane = tid & 63;
    int wv   = tid >> 6;        // 0..7
    int lrow = lane & 15;
    int lgrp = lane >> 4;       // 0..3
    int ch0  = lane * 4;        // 4 channels per lane

    // zero row 49 (im2col OOB target)
    if (tid < 128) ((float*)(lds + 49 * 512))[tid] = 0.f;

    const float* rp = rois + (size_t)roi * 6;
    int   bidx = (int)rp[0];
    float cx0 = rp[1], cy0 = rp[2], rw0 = rp[3], rh0 = rp[4], th = rp[5];
    float ct = cosf(th), st = sinf(th);

    // per-lane im2col row precompute
    int pys[4], pxs[4];
    bool prow[4];
#pragma unroll
    for (int mt = 0; mt < 4; ++mt) {
        int pix = mt * 16 + lrow;
        pys[mt] = pix / 7;
        pxs[mt] = pix - pys[mt] * 7;
        prow[mt] = pix < NPIX;
    }
    int lg16 = lgrp * 16;

    auto conv = [&](const unsigned short* __restrict__ Bt, f32x4 (&acc)[4][2]) {
        const f32x4 FZ = {0.f, 0.f, 0.f, 0.f};
#pragma unroll
        for (int mt = 0; mt < 4; ++mt) {
            acc[mt][0] = FZ; acc[mt][1] = FZ;
        }
        const unsigned short* bp0 = Bt + (size_t)(wv * 32 + lrow) * KTOT + lgrp * 8;
        const unsigned short* bp1 = Bt + (size_t)(wv * 32 + 16 + lrow) * KTOT + lgrp * 8;
        for (int t = 0; t < 9; ++t) {
            int dy = t / 3 - 1, dx = (t % 3) - 1;
            int rowoff[4], swz[4];
#pragma unroll
            for (int mt = 0; mt < 4; ++mt) {
                int oy = pys[mt] + dy, ox = pxs[mt] + dx;
                bool v = prow[mt] && ((unsigned)oy < 7u) && ((unsigned)ox < 7u);
                int np = v ? (oy * 7 + ox) : 49;
                rowoff[mt] = np * 512;
                swz[mt] = (np & 7) << 4;
            }
#pragma unroll
            for (int c8 = 0; c8 < 8; ++c8) {
                int kb = c8 * 64 + lg16;
                bf16x8 a[4];
#pragma unroll
                for (int mt = 0; mt < 4; ++mt)
                    a[mt] = *(const bf16x8*)(lds + rowoff[mt] + (kb ^ swz[mt]));
                int ke = (t * 8 + c8) * 32;
                bf16x8 b0 = *(const bf16x8*)(bp0 + ke);
                bf16x8 b1 = *(const bf16x8*)(bp1 + ke);
#pragma unroll
                for (int mt = 0; mt < 4; ++mt) {
                    acc[mt][0] = __builtin_amdgcn_mfma_f32_16x16x32_bf16(a[mt], b0, acc[mt][0], 0, 0, 0);
                    acc[mt][1] = __builtin_amdgcn_mfma_f32_16x16x32_bf16(a[mt], b1, acc[mt][1], 0, 0, 0);
                }
            }
        }
    };

    const unsigned short* nh[4] = {nh0, nh1, nh2, nh3};
    const float* raw[4] = {raw0, raw1, raw2, raw3};
    const int Hs[4] = {256, 128, 64, 32};
    const float sc[4] = {0.25f, 0.125f, 0.0625f, 0.03125f};

    f32x4 sum[4][2];
    {
        const f32x4 FZ = {0.f, 0.f, 0.f, 0.f};
#pragma unroll
        for (int mt = 0; mt < 4; ++mt) { sum[mt][0] = FZ; sum[mt][1] = FZ; }
    }

    for (int lev = 0; lev < 4; ++lev) {
        int H = Hs[lev], W = Hs[lev];
        float s = sc[lev];
        float cx = cx0 * s, cy = cy0 * s, rw = rw0 * s, rh = rh0 * s;
        float bw = rw * (1.0f / P), bh = rh * (1.0f / P);
        float fH = (float)H, fW = (float)W;
        bool staged = (modes >> lev) & 1;
        const unsigned short* f = nh[lev];
        const float* fr = raw[lev];

        __syncthreads();   // previous conv done reading lds
        // ---- rotated RoIAlign: one wave per bin, 4 ch per lane ----
        for (int bin = wv; bin < NPIX; bin += 8) {
            int py = bin / 7, px = bin - py * 7;
            float a0 = 0.f, a1 = 0.f, a2 = 0.f, a3 = 0.f;
#pragma unroll
            for (int smp = 0; smp < 4; ++smp) {
                int sy = smp >> 1, sx = smp & 1;
                float offy = (float)py + 0.25f + 0.5f * (float)sy;
                float offx = (float)px + 0.25f + 0.5f * (float)sx;
                float yy = offy * bh - rh * 0.5f;
                float xx = offx * bw - rw * 0.5f;
                float X = xx * ct + yy * st + cx;
                float Y = yy * ct - xx * st + cy;
                if (Y > -1.0f && Y < fH && X > -1.0f && X < fW) {
                    float Yc = fmaxf(Y, 0.f), Xc = fmaxf(X, 0.f);
                    int y0 = min((int)Yc, H - 1);
                    int x0 = min((int)Xc, W - 1);
                    int y1 = min(y0 + 1, H - 1), x1 = min(x0 + 1, W - 1);
                    if (y0 >= H - 1) Yc = (float)(H - 1);
                    if (x0 >= W - 1) Xc = (float)(W - 1);
                    float ly = Yc - (float)y0, lx = Xc - (float)x0;
                    float hy = 1.f - ly, hx = 1.f - lx;
                    float w00 = hy * hx, w01 = hy * lx, w10 = ly * hx, w11 = ly * lx;
                    if (staged) {
                        size_t r0 = (size_t)(bidx * H + y0) * W;
                        size_t r1 = (size_t)(bidx * H + y1) * W;
                        const unsigned short* p00 = f + ((r0 + x0) << 8) + ch0;
                        const unsigned short* p01 = f + ((r0 + x1) << 8) + ch0;
                        const unsigned short* p10 = f + ((r1 + x0) << 8) + ch0;
                        const unsigned short* p11 = f + ((r1 + x1) << 8) + ch0;
                        uint2 u00 = *(const uint2*)p00;
                        uint2 u01 = *(const uint2*)p01;
                        uint2 u10 = *(const uint2*)p10;
                        uint2 u11 = *(const uint2*)p11;
                        a0 += w00 * blo(u00.x) + w01 * blo(u01.x) + w10 * blo(u10.x) + w11 * blo(u11.x);
                        a1 += w00 * bhi(u00.x) + w01 * bhi(u01.x) + w10 * bhi(u10.x) + w11 * bhi(u11.x);
                        a2 += w00 * blo(u00.y) + w01 * blo(u01.y) + w10 * blo(u10.y) + w11 * blo(u11.y);
                        a3 += w00 * bhi(u00.y) + w01 * bhi(u01.y) + w10 * bhi(u10.y) + w11 * bhi(u11.y);
                    } else {
                        // direct NCHW f32 gather
                        size_t hw = (size_t)H * W;
                        size_t i00 = (size_t)y0 * W + x0, i01 = (size_t)y0 * W + x1;
                        size_t i10 = (size_t)y1 * W + x0, i11 = (size_t)y1 * W + x1;
                        const float* fp0 = fr + ((size_t)bidx * CCH + ch0) * hw;
                        float* accp[4] = {&a0, &a1, &a2, &a3};
#pragma unroll
                        for (int cc = 0; cc < 4; ++cc) {
                            const float* fp = fp0 + (size_t)cc * hw;
                            *accp[cc] += w00 * fp[i00] + w01 * fp[i01] + w10 * fp[i10] + w11 * fp[i11];
                        }
                    }
                }
            }
            unsigned int q01 = (unsigned)f2bf(a0 * 0.25f) | ((unsigned)f2bf(a1 * 0.25f) << 16);
            unsigned int q23 = (unsigned)f2bf(a2 * 0.25f) | ((unsigned)f2bf(a3 * 0.25f) << 16);
            int off = bin * 512 + ((lane * 8) ^ ((bin & 7) << 4));
            *(uint2*)(lds + off) = make_uint2(q01, q23);
        }
        __syncthreads();

        // ---- pre conv + bias + relu, accumulate ----
        f32x4 cacc[4][2];
        conv(btpre, cacc);
#pragma unroll
        for (int nt = 0; nt < 2; ++nt) {
            int co = wv * 32 + nt * 16 + lrow;
            float bs = pre_b[co];
#pragma unroll
            for (int mt = 0; mt < 4; ++mt)
#pragma unroll
                for (int r = 0; r < 4; ++r)
                    sum[mt][nt][r] += fmaxf(cacc[mt][nt][r] + bs, 0.f);
        }
    }

    // ---- stage acc (bf16) into lds as post-conv input ----
    __syncthreads();
#pragma unroll
    for (int nt = 0; nt < 2; ++nt) {
        int co = wv * 32 + nt * 16 + lrow;
#pragma unroll
        for (int mt = 0; mt < 4; ++mt)
#pragma unroll
            for (int r = 0; r < 4; ++r) {
                int pix = mt * 16 + lgrp * 4 + r;
                if (pix < NPIX) {
                    int off = pix * 512 + ((co * 2) ^ ((pix & 7) << 4));
                    *(unsigned short*)(lds + off) = f2bf(sum[mt][nt][r]);
                }
            }
    }
    __syncthreads();

    // ---- post conv ----
    f32x4 pacc[4][2];
    conv(btpost, pacc);

    // ---- epilogue: bias + relu, direct f32 stores (out is FLOAT32) ----
    float* og = out + (size_t)roi * (NPIX * CCH);
#pragma unroll
    for (int nt = 0; nt < 2; ++nt) {
        int co = wv * 32 + nt * 16 + lrow;
        float bs = post_b[co];
#pragma unroll
        for (int mt = 0; mt < 4; ++mt)
#pragma unroll
            for (int r = 0; r < 4; ++r) {
                int pix = mt * 16 + lgrp * 4 + r;
                if (pix < NPIX)
                    og[co * NPIX + pix] = fmaxf(pacc[mt][nt][r] + bs, 0.f);
            }
    }
}

extern "C" void kernel_launch(void* const* d_in, const int* in_sizes, int n_in,
                              void* d_out, int out_size, void* d_ws, size_t ws_size,
                              hipStream_t stream) {
    const float* feats[4] = {(const float*)d_in[0], (const float*)d_in[1],
                             (const float*)d_in[2], (const float*)d_in[3]};
    const float* rois   = (const float*)d_in[4];
    const float* pre_w  = (const float*)d_in[5];
    const float* pre_b  = (const float*)d_in[6];
    const float* post_w = (const float*)d_in[7];
    const float* post_b = (const float*)d_in[8];

    int nroi = in_sizes[4] / 6;
    int B = in_sizes[0] / (CCH * 256 * 256);
    const int Hs[4] = {256, 128, 64, 32};

    // ---- ws_size-adaptive workspace plan: weights first, then levels greedily ----
    char* ws = (char*)d_ws;
    size_t off = 0;
    auto take = [&](size_t bytes) -> void* {
        void* p = ws + off;
        off += (bytes + 255) & ~(size_t)255;
        return p;
    };
    unsigned short* btpre  = (unsigned short*)take((size_t)CCH * KTOT * 2);
    unsigned short* btpost = (unsigned short*)take((size_t)CCH * KTOT * 2);

    unsigned short* nh[4] = {nullptr, nullptr, nullptr, nullptr};
    int modes = 0;
    for (int l = 0; l < 4; ++l) {
        size_t need = (size_t)B * Hs[l] * Hs[l] * CCH * 2;
        if (off + need <= ws_size) {
            nh[l] = (unsigned short*)take(need);
            modes |= (1 << l);
        }
    }

    for (int l = 0; l < 4; ++l) {
        if (!(modes & (1 << l))) continue;
        dim3 g(Hs[l] / 32, CCH / 32, B * Hs[l]);
        nhwc_transpose_kernel<<<g, 256, 0, stream>>>(feats[l], nh[l], Hs[l], Hs[l]);
    }
    wtrans_kernel<<<(2 * CCH * KTOT + 255) / 256, 256, 0, stream>>>(pre_w, post_w, btpre, btpost);
    fused_roi_kernel<<<nroi, THREADS, 0, stream>>>(rois, nh[0], nh[1], nh[2], nh[3],
                                                   feats[0], feats[1], feats[2], feats[3],
                                                   modes,
                                                   btpre, btpost, pre_b, post_b,
                                                   (float*)d_out);
}

// Round 6
// 387.806 us; speedup vs baseline: 1.3006x; 1.3006x over previous
//
#include <hip/hip_runtime.h>
#include <hip/hip_bf16.h>

#define P 7
#define CCH 256
#define NPIX 49
#define KTOT 2304
#define TILE 25088              // 49 * 512 bytes per level tile
#define ZOFF (2 * TILE)         // zero row offset
#define LDSZ (2 * TILE + 512)   // 50688 B

typedef __bf16 bf16x8 __attribute__((ext_vector_type(8)));
typedef float f32x4 __attribute__((ext_vector_type(4)));

__device__ __forceinline__ unsigned short f2bf(float f) {
    unsigned int u = __float_as_uint(f);
    unsigned int r = (u + 0x7fffu + ((u >> 16) & 1u)) >> 16;
    return (unsigned short)r;
}
__device__ __forceinline__ float blo(unsigned int u) { return __uint_as_float(u << 16); }
__device__ __forceinline__ float bhi(unsigned int u) { return __uint_as_float(u & 0xffff0000u); }

// NCHW f32 -> NHWC bf16 (per level), 32x32 tile transpose over (c,x)
__global__ void nhwc_transpose_kernel(const float* __restrict__ src,
                                      unsigned short* __restrict__ dst,
                                      int H, int W) {
    __shared__ float tile[32][33];
    int x0 = blockIdx.x * 32;
    int c0 = blockIdx.y * 32;
    int bz = blockIdx.z;            // b*H + y
    int b = bz / H, y = bz - b * H;
    int tx = threadIdx.x & 31, ty = threadIdx.x >> 5;   // 256 threads
    const float* s = src + ((size_t)(b * CCH + c0) * H + y) * W + x0;
#pragma unroll
    for (int j = 0; j < 4; ++j) {
        int row = ty + j * 8;
        tile[row][tx] = s[(size_t)row * H * W + tx];
    }
    __syncthreads();
    unsigned short* d = dst + ((size_t)bz * W + x0) * CCH + c0;
#pragma unroll
    for (int j = 0; j < 4; ++j) {
        int row = ty + j * 8;
        d[(size_t)row * CCH + tx] = f2bf(tile[tx][row]);
    }
}

// w[co][ci][ky][kx] f32 -> Bt[co][k] bf16 with k = (ky*3+kx)*256 + ci
__global__ void wtrans_kernel(const float* __restrict__ pre_w,
                              const float* __restrict__ post_w,
                              unsigned short* __restrict__ btpre,
                              unsigned short* __restrict__ btpost) {
    int idx = blockIdx.x * 256 + threadIdx.x;
    const int total = CCH * KTOT;
    if (idx >= 2 * total) return;
    const float* w = pre_w;
    unsigned short* o = btpre;
    int r = idx;
    if (r >= total) { r -= total; w = post_w; o = btpost; }
    int co = r / KTOT, k = r - co * KTOT;
    int t = k >> 8, ci = k & 255;
    o[r] = f2bf(w[(size_t)(co * CCH + ci) * 9 + t]);
}

// ============================================================================
// One block = one roi. 1024 threads = 16 waves, nt=1 (16 co per wave).
// Phases: RA{0,1} -> convA (one B stream, 2 levels) -> RA{2,3} -> convB
//         -> stage f32 sum (one bf16 rounding, R3 bit-path) -> post-conv.
// ============================================================================
__launch_bounds__(1024)
__global__ void fused_roi_kernel(const float* __restrict__ rois,
                                 const unsigned short* __restrict__ nh0,
                                 const unsigned short* __restrict__ nh1,
                                 const unsigned short* __restrict__ nh2,
                                 const unsigned short* __restrict__ nh3,
                                 const float* __restrict__ raw0,
                                 const float* __restrict__ raw1,
                                 const float* __restrict__ raw2,
                                 const float* __restrict__ raw3,
                                 int modes,
                                 const unsigned short* __restrict__ btpre,
                                 const unsigned short* __restrict__ btpost,
                                 const float* __restrict__ pre_b,
                                 const float* __restrict__ post_b,
                                 float* __restrict__ out) {
    __shared__ __align__(16) char lds[LDSZ];

    int roi  = blockIdx.x;
    int tid  = threadIdx.x;
    int lane = tid & 63;
    int wv   = tid >> 6;        // 0..15
    int lrow = lane & 15;
    int lgrp = lane >> 4;       // 0..3
    int ch0  = lane * 4;
    int co   = wv * 16 + lrow;  // this lane's output channel (nt=1)

    if (tid < 128) ((float*)(lds + ZOFF))[tid] = 0.f;

    const float* rp = rois + (size_t)roi * 6;
    int   bidx = (int)rp[0];
    float cx0 = rp[1], cy0 = rp[2], rw0 = rp[3], rh0 = rp[4], th = rp[5];
    float ct = cosf(th), st = sinf(th);

    const unsigned short* nh[4] = {nh0, nh1, nh2, nh3};
    const float* raw[4] = {raw0, raw1, raw2, raw3};
    const int Hs[4] = {256, 128, 64, 32};
    const float scl[4] = {0.25f, 0.125f, 0.0625f, 0.03125f};

    // ---- rotated RoIAlign for one level-pair: wave wv -> pair member wv&1,
    //      bins (wv>>1) stride 8; writes tile (wv&1) ----
    auto ra_pair = [&](int p) {
        int ml = wv & 1;            // tile index within pair
        int gl = p * 2 + ml;        // global level
        int H = Hs[gl], W = H;
        float s = scl[gl];
        float cx = cx0 * s, cy = cy0 * s, rw = rw0 * s, rh = rh0 * s;
        float bw = rw * (1.0f / P), bh = rh * (1.0f / P);
        float fH = (float)H, fW = (float)W;
        bool staged = (modes >> gl) & 1;
        const unsigned short* f = nh[gl];
        const float* fr = raw[gl];
        for (int bin = (wv >> 1); bin < NPIX; bin += 8) {
            int py = bin / 7, px = bin - py * 7;
            float a0 = 0.f, a1 = 0.f, a2 = 0.f, a3 = 0.f;
#pragma unroll
            for (int smp = 0; smp < 4; ++smp) {
                int sy = smp >> 1, sx = smp & 1;
                float offy = (float)py + 0.25f + 0.5f * (float)sy;
                float offx = (float)px + 0.25f + 0.5f * (float)sx;
                float yy = offy * bh - rh * 0.5f;
                float xx = offx * bw - rw * 0.5f;
                float X = xx * ct + yy * st + cx;
                float Y = yy * ct - xx * st + cy;
                if (Y > -1.0f && Y < fH && X > -1.0f && X < fW) {
                    float Yc = fmaxf(Y, 0.f), Xc = fmaxf(X, 0.f);
                    int y0 = min((int)Yc, H - 1);
                    int x0 = min((int)Xc, W - 1);
                    int y1 = min(y0 + 1, H - 1), x1 = min(x0 + 1, W - 1);
                    if (y0 >= H - 1) Yc = (float)(H - 1);
                    if (x0 >= W - 1) Xc = (float)(W - 1);
                    float ly = Yc - (float)y0, lx = Xc - (float)x0;
                    float hy = 1.f - ly, hx = 1.f - lx;
                    float w00 = hy * hx, w01 = hy * lx, w10 = ly * hx, w11 = ly * lx;
                    if (staged) {
                        size_t r0 = (size_t)(bidx * H + y0) * W;
                        size_t r1 = (size_t)(bidx * H + y1) * W;
                        uint2 u00 = *(const uint2*)(f + ((r0 + x0) << 8) + ch0);
                        uint2 u01 = *(const uint2*)(f + ((r0 + x1) << 8) + ch0);
                        uint2 u10 = *(const uint2*)(f + ((r1 + x0) << 8) + ch0);
                        uint2 u11 = *(const uint2*)(f + ((r1 + x1) << 8) + ch0);
                        a0 += w00 * blo(u00.x) + w01 * blo(u01.x) + w10 * blo(u10.x) + w11 * blo(u11.x);
                        a1 += w00 * bhi(u00.x) + w01 * bhi(u01.x) + w10 * bhi(u10.x) + w11 * bhi(u11.x);
                        a2 += w00 * blo(u00.y) + w01 * blo(u01.y) + w10 * blo(u10.y) + w11 * blo(u11.y);
                        a3 += w00 * bhi(u00.y) + w01 * bhi(u01.y) + w10 * bhi(u10.y) + w11 * bhi(u11.y);
                    } else {
                        size_t hw = (size_t)H * W;
                        size_t i00 = (size_t)y0 * W + x0, i01 = (size_t)y0 * W + x1;
                        size_t i10 = (size_t)y1 * W + x0, i11 = (size_t)y1 * W + x1;
                        const float* fp0 = fr + ((size_t)bidx * CCH + ch0) * hw;
                        float* accp[4] = {&a0, &a1, &a2, &a3};
#pragma unroll
                        for (int cc = 0; cc < 4; ++cc) {
                            const float* fp = fp0 + (size_t)cc * hw;
                            *accp[cc] += w00 * fp[i00] + w01 * fp[i01] + w10 * fp[i10] + w11 * fp[i11];
                        }
                    }
                }
            }
            unsigned int q01 = (unsigned)f2bf(a0 * 0.25f) | ((unsigned)f2bf(a1 * 0.25f) << 16);
            unsigned int q23 = (unsigned)f2bf(a2 * 0.25f) | ((unsigned)f2bf(a3 * 0.25f) << 16);
            int off = ml * TILE + bin * 512 + ((lane * 8) ^ ((bin & 7) << 4));
            *(uint2*)(lds + off) = make_uint2(q01, q23);
        }
    };

    // per-lane im2col row precompute
    int pys[4], pxs[4];
    bool prow[4];
#pragma unroll
    for (int mt = 0; mt < 4; ++mt) {
        int pix = mt * 16 + lrow;
        pys[mt] = pix / 7;
        pxs[mt] = pix - pys[mt] * 7;
        prow[mt] = pix < NPIX;
    }
    int lg16 = lgrp * 16;

    // ---- conv over the two resident tiles with ONE B stream ----
    auto conv_pair = [&](const unsigned short* __restrict__ Bt, f32x4 (&acc)[2][4]) {
        const f32x4 FZ = {0.f, 0.f, 0.f, 0.f};
#pragma unroll
        for (int lv = 0; lv < 2; ++lv)
#pragma unroll
            for (int mt = 0; mt < 4; ++mt) acc[lv][mt] = FZ;
        const unsigned short* bp = Bt + (size_t)co * KTOT + lgrp * 8;
        for (int t = 0; t < 9; ++t) {
            int dy = t / 3 - 1, dx = (t % 3) - 1;
            int roff[4], swz[4];
#pragma unroll
            for (int mt = 0; mt < 4; ++mt) {
                int oy = pys[mt] + dy, ox = pxs[mt] + dx;
                bool v = prow[mt] && ((unsigned)oy < 7u) && ((unsigned)ox < 7u);
                int np = oy * 7 + ox;
                roff[mt] = v ? np * 512 : (ZOFF - 0);   // level-local; +TILE for lv=1 handled below
                swz[mt]  = v ? ((np & 7) << 4) : 16;
                if (!v) roff[mt] = ZOFF;                 // absolute zero row
            }
#pragma unroll
            for (int c8 = 0; c8 < 8; ++c8) {
                int kb = c8 * 64 + lg16;
                int ke = (t * 8 + c8) * 32;
                bf16x8 b = *(const bf16x8*)(bp + ke);
#pragma unroll
                for (int mt = 0; mt < 4; ++mt) {
                    int lo = kb ^ swz[mt];
                    bf16x8 a0 = *(const bf16x8*)(lds + roff[mt] + lo);
                    acc[0][mt] = __builtin_amdgcn_mfma_f32_16x16x32_bf16(a0, b, acc[0][mt], 0, 0, 0);
                    bf16x8 a1 = *(const bf16x8*)(lds + (roff[mt] == ZOFF ? ZOFF : roff[mt] + TILE) + lo);
                    acc[1][mt] = __builtin_amdgcn_mfma_f32_16x16x32_bf16(a1, b, acc[1][mt], 0, 0, 0);
                }
            }
        }
    };

    float bs_pre = pre_b[co];
    f32x4 sum[4];
    {
        const f32x4 FZ = {0.f, 0.f, 0.f, 0.f};
#pragma unroll
        for (int mt = 0; mt < 4; ++mt) sum[mt] = FZ;
    }

    // ===== pair 0: levels 0,1 =====
    ra_pair(0);
    __syncthreads();
    {
        f32x4 acc[2][4];
        conv_pair(btpre, acc);
#pragma unroll
        for (int lv = 0; lv < 2; ++lv)
#pragma unroll
            for (int mt = 0; mt < 4; ++mt)
#pragma unroll
                for (int r = 0; r < 4; ++r)
                    sum[mt][r] += fmaxf(acc[lv][mt][r] + bs_pre, 0.f);
    }
    __syncthreads();   // conv A reads done before RA overwrites tiles

    // ===== pair 1: levels 2,3 =====
    ra_pair(1);
    __syncthreads();
    {
        f32x4 acc[2][4];
        conv_pair(btpre, acc);
#pragma unroll
        for (int lv = 0; lv < 2; ++lv)
#pragma unroll
            for (int mt = 0; mt < 4; ++mt)
#pragma unroll
                for (int r = 0; r < 4; ++r)
                    sum[mt][r] += fmaxf(acc[lv][mt][r] + bs_pre, 0.f);
    }
    __syncthreads();   // conv B reads done before staging overwrites tile 0

    // ---- stage f32 sum -> bf16 tile 0 (single rounding, R3 bit-path) ----
#pragma unroll
    for (int mt = 0; mt < 4; ++mt)
#pragma unroll
        for (int r = 0; r < 4; ++r) {
            int pix = mt * 16 + lgrp * 4 + r;
            if (pix < NPIX) {
                int off = pix * 512 + ((co * 2) ^ ((pix & 7) << 4));
                *(unsigned short*)(lds + off) = f2bf(sum[mt][r]);
            }
        }
    __syncthreads();

    // ---- post conv on tile 0 ----
    f32x4 pacc[4];
    {
        const f32x4 FZ = {0.f, 0.f, 0.f, 0.f};
#pragma unroll
        for (int mt = 0; mt < 4; ++mt) pacc[mt] = FZ;
    }
    {
        const unsigned short* bp = btpost + (size_t)co * KTOT + lgrp * 8;
        for (int t = 0; t < 9; ++t) {
            int dy = t / 3 - 1, dx = (t % 3) - 1;
            int roff[4], swz[4];
#pragma unroll
            for (int mt = 0; mt < 4; ++mt) {
                int oy = pys[mt] + dy, ox = pxs[mt] + dx;
                bool v = prow[mt] && ((unsigned)oy < 7u) && ((unsigned)ox < 7u);
                int np = oy * 7 + ox;
                roff[mt] = v ? np * 512 : ZOFF;
                swz[mt]  = v ? ((np & 7) << 4) : 16;
            }
#pragma unroll
            for (int c8 = 0; c8 < 8; ++c8) {
                int kb = c8 * 64 + lg16;
                int ke = (t * 8 + c8) * 32;
                bf16x8 b = *(const bf16x8*)(bp + ke);
#pragma unroll
                for (int mt = 0; mt < 4; ++mt) {
                    bf16x8 a = *(const bf16x8*)(lds + roff[mt] + (kb ^ swz[mt]));
                    pacc[mt] = __builtin_amdgcn_mfma_f32_16x16x32_bf16(a, b, pacc[mt], 0, 0, 0);
                }
            }
        }
    }

    // ---- epilogue: bias + relu -> f32 out ----
    float bs_post = post_b[co];
    float* og = out + (size_t)roi * (NPIX * CCH);
#pragma unroll
    for (int mt = 0; mt < 4; ++mt)
#pragma unroll
        for (int r = 0; r < 4; ++r) {
            int pix = mt * 16 + lgrp * 4 + r;
            if (pix < NPIX)
                og[co * NPIX + pix] = fmaxf(pacc[mt][r] + bs_post, 0.f);
        }
}

extern "C" void kernel_launch(void* const* d_in, const int* in_sizes, int n_in,
                              void* d_out, int out_size, void* d_ws, size_t ws_size,
                              hipStream_t stream) {
    const float* feats[4] = {(const float*)d_in[0], (const float*)d_in[1],
                             (const float*)d_in[2], (const float*)d_in[3]};
    const float* rois   = (const float*)d_in[4];
    const float* pre_w  = (const float*)d_in[5];
    const float* pre_b  = (const float*)d_in[6];
    const float* post_w = (const float*)d_in[7];
    const float* post_b = (const float*)d_in[8];

    int nroi = in_sizes[4] / 6;
    int B = in_sizes[0] / (CCH * 256 * 256);
    const int Hs[4] = {256, 128, 64, 32};

    // ws plan: weights, then feature levels greedily
    char* ws = (char*)d_ws;
    size_t off = 0;
    auto take = [&](size_t bytes) -> void* {
        void* p = ws + off;
        off += (bytes + 255) & ~(size_t)255;
        return p;
    };
    unsigned short* btpre  = (unsigned short*)take((size_t)CCH * KTOT * 2);
    unsigned short* btpost = (unsigned short*)take((size_t)CCH * KTOT * 2);

    unsigned short* nh[4] = {nullptr, nullptr, nullptr, nullptr};
    int modes = 0;
    for (int l = 0; l < 4; ++l) {
        size_t need = (size_t)B * Hs[l] * Hs[l] * CCH * 2;
        if (off + need <= ws_size) {
            nh[l] = (unsigned short*)take(need);
            modes |= (1 << l);
        }
    }

    for (int l = 0; l < 4; ++l) {
        if (!(modes & (1 << l))) continue;
        dim3 g(Hs[l] / 32, CCH / 32, B * Hs[l]);
        nhwc_transpose_kernel<<<g, 256, 0, stream>>>(feats[l], nh[l], Hs[l], Hs[l]);
    }
    wtrans_kernel<<<(2 * CCH * KTOT + 255) / 256, 256, 0, stream>>>(pre_w, post_w, btpre, btpost);

    fused_roi_kernel<<<nroi, 1024, 0, stream>>>(rois, nh[0], nh[1], nh[2], nh[3],
                                                feats[0], feats[1], feats[2], feats[3],
                                                modes, btpre, btpost, pre_b, post_b,
                                                (float*)d_out);
}

// Round 7
// 381.380 us; speedup vs baseline: 1.3225x; 1.0168x over previous
//
#include <hip/hip_runtime.h>
#include <hip/hip_bf16.h>

#define P 7
#define CCH 256
#define NPIX 49
#define KTOT 2304
#define THREADS 512
#define TILE 25088              // 49 * 512 bytes per level tile
#define ZOFF (2 * TILE)         // zero row offset
#define LDSZ (2 * TILE + 512)   // 50688 B

typedef __bf16 bf16x8 __attribute__((ext_vector_type(8)));
typedef float f32x4 __attribute__((ext_vector_type(4)));

__device__ __forceinline__ unsigned short f2bf(float f) {
    unsigned int u = __float_as_uint(f);
    unsigned int r = (u + 0x7fffu + ((u >> 16) & 1u)) >> 16;
    return (unsigned short)r;
}
__device__ __forceinline__ float blo(unsigned int u) { return __uint_as_float(u << 16); }
__device__ __forceinline__ float bhi(unsigned int u) { return __uint_as_float(u & 0xffff0000u); }

// NCHW f32 -> NHWC bf16 (per level), 32x32 tile transpose over (c,x)
__global__ void nhwc_transpose_kernel(const float* __restrict__ src,
                                      unsigned short* __restrict__ dst,
                                      int H, int W) {
    __shared__ float tile[32][33];
    int x0 = blockIdx.x * 32;
    int c0 = blockIdx.y * 32;
    int bz = blockIdx.z;            // b*H + y
    int b = bz / H, y = bz - b * H;
    int tx = threadIdx.x & 31, ty = threadIdx.x >> 5;   // 256 threads
    const float* s = src + ((size_t)(b * CCH + c0) * H + y) * W + x0;
#pragma unroll
    for (int j = 0; j < 4; ++j) {
        int row = ty + j * 8;
        tile[row][tx] = s[(size_t)row * H * W + tx];
    }
    __syncthreads();
    unsigned short* d = dst + ((size_t)bz * W + x0) * CCH + c0;
#pragma unroll
    for (int j = 0; j < 4; ++j) {
        int row = ty + j * 8;
        d[(size_t)row * CCH + tx] = f2bf(tile[tx][row]);
    }
}

// w[co][ci][ky][kx] f32 -> Bt[co][k] bf16 with k = (ky*3+kx)*256 + ci
__global__ void wtrans_kernel(const float* __restrict__ pre_w,
                              const float* __restrict__ post_w,
                              unsigned short* __restrict__ btpre,
                              unsigned short* __restrict__ btpost) {
    int idx = blockIdx.x * 256 + threadIdx.x;
    const int total = CCH * KTOT;
    if (idx >= 2 * total) return;
    const float* w = pre_w;
    unsigned short* o = btpre;
    int r = idx;
    if (r >= total) { r -= total; w = post_w; o = btpost; }
    int co = r / KTOT, k = r - co * KTOT;
    int t = k >> 8, ci = k & 255;
    o[r] = f2bf(w[(size_t)(co * CCH + ci) * 9 + t]);
}

// ============================================================================
// One block = one roi. 512 threads = 8 waves, nt=2 (co and co+128 per lane).
// Phases: RA{0,1} -> convA (1 B stream, 2 tiles, 16 MFMA : 8 ds_read)
//         -> RA{2,3} -> convB -> stage f32 sum (single bf16 rounding)
//         -> post-conv (nt=2).
// ============================================================================
__launch_bounds__(THREADS, 4)
__global__ void fused_roi_kernel(const float* __restrict__ rois,
                                 const unsigned short* __restrict__ nh0,
                                 const unsigned short* __restrict__ nh1,
                                 const unsigned short* __restrict__ nh2,
                                 const unsigned short* __restrict__ nh3,
                                 const float* __restrict__ raw0,
                                 const float* __restrict__ raw1,
                                 const float* __restrict__ raw2,
                                 const float* __restrict__ raw3,
                                 int modes,
                                 const unsigned short* __restrict__ btpre,
                                 const unsigned short* __restrict__ btpost,
                                 const float* __restrict__ pre_b,
                                 const float* __restrict__ post_b,
                                 float* __restrict__ out) {
    __shared__ __align__(16) char lds[LDSZ];

    int roi  = blockIdx.x;
    int tid  = threadIdx.x;
    int lane = tid & 63;
    int wv   = tid >> 6;        // 0..7
    int lrow = lane & 15;
    int lgrp = lane >> 4;       // 0..3
    int ch0  = lane * 4;
    int co0  = wv * 16 + lrow;  // first output channel (0..127)
    int co1  = co0 + 128;       // second output channel

    if (tid < 128) ((float*)(lds + ZOFF))[tid] = 0.f;

    const float* rp = rois + (size_t)roi * 6;
    int   bidx = (int)rp[0];
    float cx0 = rp[1], cy0 = rp[2], rw0 = rp[3], rh0 = rp[4], th = rp[5];
    float ct = cosf(th), st = sinf(th);

    const unsigned short* nh[4] = {nh0, nh1, nh2, nh3};
    const float* raw[4] = {raw0, raw1, raw2, raw3};
    const int Hs[4] = {256, 128, 64, 32};
    const float scl[4] = {0.25f, 0.125f, 0.0625f, 0.03125f};

    // ---- rotated RoIAlign for one level-pair: wave wv -> tile wv&1,
    //      bins (wv>>1) stride 4 ----
    auto ra_pair = [&](int p) {
        int ml = wv & 1;
        int gl = p * 2 + ml;
        int H = Hs[gl], W = H;
        float s = scl[gl];
        float cx = cx0 * s, cy = cy0 * s, rw = rw0 * s, rh = rh0 * s;
        float bw = rw * (1.0f / P), bh = rh * (1.0f / P);
        float fH = (float)H, fW = (float)W;
        bool staged = (modes >> gl) & 1;
        const unsigned short* f = nh[gl];
        const float* fr = raw[gl];
        for (int bin = (wv >> 1); bin < NPIX; bin += 4) {
            int py = bin / 7, px = bin - py * 7;
            float a0 = 0.f, a1 = 0.f, a2 = 0.f, a3 = 0.f;
#pragma unroll
            for (int smp = 0; smp < 4; ++smp) {
                int sy = smp >> 1, sx = smp & 1;
                float offy = (float)py + 0.25f + 0.5f * (float)sy;
                float offx = (float)px + 0.25f + 0.5f * (float)sx;
                float yy = offy * bh - rh * 0.5f;
                float xx = offx * bw - rw * 0.5f;
                float X = xx * ct + yy * st + cx;
                float Y = yy * ct - xx * st + cy;
                if (Y > -1.0f && Y < fH && X > -1.0f && X < fW) {
                    float Yc = fmaxf(Y, 0.f), Xc = fmaxf(X, 0.f);
                    int y0 = min((int)Yc, H - 1);
                    int x0 = min((int)Xc, W - 1);
                    int y1 = min(y0 + 1, H - 1), x1 = min(x0 + 1, W - 1);
                    if (y0 >= H - 1) Yc = (float)(H - 1);
                    if (x0 >= W - 1) Xc = (float)(W - 1);
                    float ly = Yc - (float)y0, lx = Xc - (float)x0;
                    float hy = 1.f - ly, hx = 1.f - lx;
                    float w00 = hy * hx, w01 = hy * lx, w10 = ly * hx, w11 = ly * lx;
                    if (staged) {
                        size_t r0 = (size_t)(bidx * H + y0) * W;
                        size_t r1 = (size_t)(bidx * H + y1) * W;
                        uint2 u00 = *(const uint2*)(f + ((r0 + x0) << 8) + ch0);
                        uint2 u01 = *(const uint2*)(f + ((r0 + x1) << 8) + ch0);
                        uint2 u10 = *(const uint2*)(f + ((r1 + x0) << 8) + ch0);
                        uint2 u11 = *(const uint2*)(f + ((r1 + x1) << 8) + ch0);
                        a0 += w00 * blo(u00.x) + w01 * blo(u01.x) + w10 * blo(u10.x) + w11 * blo(u11.x);
                        a1 += w00 * bhi(u00.x) + w01 * bhi(u01.x) + w10 * bhi(u10.x) + w11 * bhi(u11.x);
                        a2 += w00 * blo(u00.y) + w01 * blo(u01.y) + w10 * blo(u10.y) + w11 * blo(u11.y);
                        a3 += w00 * bhi(u00.y) + w01 * bhi(u01.y) + w10 * bhi(u10.y) + w11 * bhi(u11.y);
                    } else {
                        size_t hw = (size_t)H * W;
                        size_t i00 = (size_t)y0 * W + x0, i01 = (size_t)y0 * W + x1;
                        size_t i10 = (size_t)y1 * W + x0, i11 = (size_t)y1 * W + x1;
                        const float* fp0 = fr + ((size_t)bidx * CCH + ch0) * hw;
                        float* accp[4] = {&a0, &a1, &a2, &a3};
#pragma unroll
                        for (int cc = 0; cc < 4; ++cc) {
                            const float* fp = fp0 + (size_t)cc * hw;
                            *accp[cc] += w00 * fp[i00] + w01 * fp[i01] + w10 * fp[i10] + w11 * fp[i11];
                        }
                    }
                }
            }
            unsigned int q01 = (unsigned)f2bf(a0 * 0.25f) | ((unsigned)f2bf(a1 * 0.25f) << 16);
            unsigned int q23 = (unsigned)f2bf(a2 * 0.25f) | ((unsigned)f2bf(a3 * 0.25f) << 16);
            int off = ml * TILE + bin * 512 + ((lane * 8) ^ ((bin & 7) << 4));
            *(uint2*)(lds + off) = make_uint2(q01, q23);
        }
    };

    // per-lane im2col row precompute
    int pys[4], pxs[4];
    bool prow[4];
#pragma unroll
    for (int mt = 0; mt < 4; ++mt) {
        int pix = mt * 16 + lrow;
        pys[mt] = pix / 7;
        pxs[mt] = pix - pys[mt] * 7;
        prow[mt] = pix < NPIX;
    }
    int lg16 = lgrp * 16;

    // ---- conv over the two resident tiles: one B stream, nt=2 ----
    auto conv_pair = [&](const unsigned short* __restrict__ Bt, f32x4 (&acc)[2][4][2]) {
        const f32x4 FZ = {0.f, 0.f, 0.f, 0.f};
#pragma unroll
        for (int lv = 0; lv < 2; ++lv)
#pragma unroll
            for (int mt = 0; mt < 4; ++mt) {
                acc[lv][mt][0] = FZ; acc[lv][mt][1] = FZ;
            }
        const unsigned short* bp0 = Bt + (size_t)co0 * KTOT + lg16 / 2;
        const unsigned short* bp1 = Bt + (size_t)co1 * KTOT + lg16 / 2;
        for (int t = 0; t < 9; ++t) {
            int dy = t / 3 - 1, dx = (t % 3) - 1;
            int roff[4], swz[4];
#pragma unroll
            for (int mt = 0; mt < 4; ++mt) {
                int oy = pys[mt] + dy, ox = pxs[mt] + dx;
                bool v = prow[mt] && ((unsigned)oy < 7u) && ((unsigned)ox < 7u);
                int np = oy * 7 + ox;
                roff[mt] = v ? np * 512 : ZOFF;
                swz[mt]  = v ? ((np & 7) << 4) : 16;
            }
#pragma unroll
            for (int c8 = 0; c8 < 8; ++c8) {
                int kb = c8 * 64 + lg16;
                int ke = (t * 8 + c8) * 32;
                bf16x8 b0 = *(const bf16x8*)(bp0 + ke);
                bf16x8 b1 = *(const bf16x8*)(bp1 + ke);
#pragma unroll
                for (int mt = 0; mt < 4; ++mt) {
                    int lo = kb ^ swz[mt];
                    bf16x8 a0 = *(const bf16x8*)(lds + roff[mt] + lo);
                    bf16x8 a1 = *(const bf16x8*)(lds + (roff[mt] == ZOFF ? ZOFF : roff[mt] + TILE) + lo);
                    acc[0][mt][0] = __builtin_amdgcn_mfma_f32_16x16x32_bf16(a0, b0, acc[0][mt][0], 0, 0, 0);
                    acc[0][mt][1] = __builtin_amdgcn_mfma_f32_16x16x32_bf16(a0, b1, acc[0][mt][1], 0, 0, 0);
                    acc[1][mt][0] = __builtin_amdgcn_mfma_f32_16x16x32_bf16(a1, b0, acc[1][mt][0], 0, 0, 0);
                    acc[1][mt][1] = __builtin_amdgcn_mfma_f32_16x16x32_bf16(a1, b1, acc[1][mt][1], 0, 0, 0);
                }
            }
        }
    };

    float bs0 = pre_b[co0], bs1 = pre_b[co1];
    f32x4 sum[4][2];
    {
        const f32x4 FZ = {0.f, 0.f, 0.f, 0.f};
#pragma unroll
        for (int mt = 0; mt < 4; ++mt) { sum[mt][0] = FZ; sum[mt][1] = FZ; }
    }

    // ===== pair 0: levels 0,1 =====
    ra_pair(0);
    __syncthreads();
    {
        f32x4 acc[2][4][2];
        conv_pair(btpre, acc);
#pragma unroll
        for (int lv = 0; lv < 2; ++lv)
#pragma unroll
            for (int mt = 0; mt < 4; ++mt)
#pragma unroll
                for (int r = 0; r < 4; ++r) {
                    sum[mt][0][r] += fmaxf(acc[lv][mt][0][r] + bs0, 0.f);
                    sum[mt][1][r] += fmaxf(acc[lv][mt][1][r] + bs1, 0.f);
                }
    }
    __syncthreads();   // conv A reads done before RA overwrites tiles

    // ===== pair 1: levels 2,3 =====
    ra_pair(1);
    __syncthreads();
    {
        f32x4 acc[2][4][2];
        conv_pair(btpre, acc);
#pragma unroll
        for (int lv = 0; lv < 2; ++lv)
#pragma unroll
            for (int mt = 0; mt < 4; ++mt)
#pragma unroll
                for (int r = 0; r < 4; ++r) {
                    sum[mt][0][r] += fmaxf(acc[lv][mt][0][r] + bs0, 0.f);
                    sum[mt][1][r] += fmaxf(acc[lv][mt][1][r] + bs1, 0.f);
                }
    }
    __syncthreads();   // conv B reads done before staging overwrites tile 0

    // ---- stage f32 sum -> bf16 tile 0 (single rounding) ----
#pragma unroll
    for (int nt = 0; nt < 2; ++nt) {
        int co = nt ? co1 : co0;
#pragma unroll
        for (int mt = 0; mt < 4; ++mt)
#pragma unroll
            for (int r = 0; r < 4; ++r) {
                int pix = mt * 16 + lgrp * 4 + r;
                if (pix < NPIX) {
                    int off = pix * 512 + ((co * 2) ^ ((pix & 7) << 4));
                    *(unsigned short*)(lds + off) = f2bf(sum[mt][nt][r]);
                }
            }
    }
    __syncthreads();

    // ---- post conv on tile 0 (nt=2) ----
    f32x4 pacc[4][2];
    {
        const f32x4 FZ = {0.f, 0.f, 0.f, 0.f};
#pragma unroll
        for (int mt = 0; mt < 4; ++mt) { pacc[mt][0] = FZ; pacc[mt][1] = FZ; }
    }
    {
        const unsigned short* bp0 = btpost + (size_t)co0 * KTOT + lg16 / 2;
        const unsigned short* bp1 = btpost + (size_t)co1 * KTOT + lg16 / 2;
        for (int t = 0; t < 9; ++t) {
            int dy = t / 3 - 1, dx = (t % 3) - 1;
            int roff[4], swz[4];
#pragma unroll
            for (int mt = 0; mt < 4; ++mt) {
                int oy = pys[mt] + dy, ox = pxs[mt] + dx;
                bool v = prow[mt] && ((unsigned)oy < 7u) && ((unsigned)ox < 7u);
                int np = oy * 7 + ox;
                roff[mt] = v ? np * 512 : ZOFF;
                swz[mt]  = v ? ((np & 7) << 4) : 16;
            }
#pragma unroll
            for (int c8 = 0; c8 < 8; ++c8) {
                int kb = c8 * 64 + lg16;
                int ke = (t * 8 + c8) * 32;
                bf16x8 b0 = *(const bf16x8*)(bp0 + ke);
                bf16x8 b1 = *(const bf16x8*)(bp1 + ke);
#pragma unroll
                for (int mt = 0; mt < 4; ++mt) {
                    bf16x8 a = *(const bf16x8*)(lds + roff[mt] + (kb ^ swz[mt]));
                    pacc[mt][0] = __builtin_amdgcn_mfma_f32_16x16x32_bf16(a, b0, pacc[mt][0], 0, 0, 0);
                    pacc[mt][1] = __builtin_amdgcn_mfma_f32_16x16x32_bf16(a, b1, pacc[mt][1], 0, 0, 0);
                }
            }
        }
    }

    // ---- epilogue: bias + relu -> f32 out ----
    float pb0 = post_b[co0], pb1 = post_b[co1];
    float* og = out + (size_t)roi * (NPIX * CCH);
#pragma unroll
    for (int mt = 0; mt < 4; ++mt)
#pragma unroll
        for (int r = 0; r < 4; ++r) {
            int pix = mt * 16 + lgrp * 4 + r;
            if (pix < NPIX) {
                og[co0 * NPIX + pix] = fmaxf(pacc[mt][0][r] + pb0, 0.f);
                og[co1 * NPIX + pix] = fmaxf(pacc[mt][1][r] + pb1, 0.f);
            }
        }
}

extern "C" void kernel_launch(void* const* d_in, const int* in_sizes, int n_in,
                              void* d_out, int out_size, void* d_ws, size_t ws_size,
                              hipStream_t stream) {
    const float* feats[4] = {(const float*)d_in[0], (const float*)d_in[1],
                             (const float*)d_in[2], (const float*)d_in[3]};
    const float* rois   = (const float*)d_in[4];
    const float* pre_w  = (const float*)d_in[5];
    const float* pre_b  = (const float*)d_in[6];
    const float* post_w = (const float*)d_in[7];
    const float* post_b = (const float*)d_in[8];

    int nroi = in_sizes[4] / 6;
    int B = in_sizes[0] / (CCH * 256 * 256);
    const int Hs[4] = {256, 128, 64, 32};

    // ws plan: weights, then feature levels greedily
    char* ws = (char*)d_ws;
    size_t off = 0;
    auto take = [&](size_t bytes) -> void* {
        void* p = ws + off;
        off += (bytes + 255) & ~(size_t)255;
        return p;
    };
    unsigned short* btpre  = (unsigned short*)take((size_t)CCH * KTOT * 2);
    unsigned short* btpost = (unsigned short*)take((size_t)CCH * KTOT * 2);

    unsigned short* nh[4] = {nullptr, nullptr, nullptr, nullptr};
    int modes = 0;
    for (int l = 0; l < 4; ++l) {
        size_t need = (size_t)B * Hs[l] * Hs[l] * CCH * 2;
        if (off + need <= ws_size) {
            nh[l] = (unsigned short*)take(need);
            modes |= (1 << l);
        }
    }

    for (int l = 0; l < 4; ++l) {
        if (!(modes & (1 << l))) continue;
        dim3 g(Hs[l] / 32, CCH / 32, B * Hs[l]);
        nhwc_transpose_kernel<<<g, 256, 0, stream>>>(feats[l], nh[l], Hs[l], Hs[l]);
    }
    wtrans_kernel<<<(2 * CCH * KTOT + 255) / 256, 256, 0, stream>>>(pre_w, post_w, btpre, btpost);

    fused_roi_kernel<<<nroi, THREADS, 0, stream>>>(rois, nh[0], nh[1], nh[2], nh[3],
                                                   feats[0], feats[1], feats[2], feats[3],
                                                   modes, btpre, btpost, pre_b, post_b,
                                                   (float*)d_out);
}